// Round 8
// baseline (164.812 us; speedup 1.0000x reference)
//
#include <hip/hip_runtime.h>
#include <math.h>

// Problem constants (fixed by setup_inputs: B=64, C=1, H=512, W=512 fp32)
static constexpr int Hdim = 512;
static constexpr int Wdim = 512;
static constexpr int HW   = Hdim * Wdim;       // 2^18 px per image
static constexpr int NIMG = 64;
static constexpr int WPR  = Wdim / 64;         // 8 uint64 words per row
static constexpr int WPI  = Hdim * WPR;        // 4096 words per image
static constexpr int RSTRIP = 16;              // rows per maskbound strip
static constexpr int SPI  = Hdim / RSTRIP;     // 32 strips per image
static constexpr int NBLK_M = NIMG * SPI;      // 2048 maskbound blocks
static constexpr int MROWS = RSTRIP + 4;       // 20 rows incl. halo
static constexpr int MWORDS = MROWS * WPR;     // 160 words per block
static constexpr int WPW = MWORDS / 4;         // 40 words per wave
static constexpr int NBLK_C = 2048;            // main kernel blocks
static constexpr int CTHREADS = NBLK_C * 256;  // 524288
static constexpr int F4TOTAL = NIMG * HW / 4;  // 4194304 float4's
static constexpr int CITERS = F4TOTAL / CTHREADS;  // 8

// d_ws layout:
//   [0, 64KB):   per-block partials (NBLK_C slots x 8 floats, 5 used)
//   [4MB, 8MB):  comb: interleaved {tword, bword} ulonglong2 per word (4 MB)
// All regions fully overwritten each call; poison-safe.

__device__ __forceinline__ unsigned long long shl1(unsigned long long c, unsigned long long l) {
    return (c << 1) | (l >> 63);   // value at x-1
}
__device__ __forceinline__ unsigned long long shr1(unsigned long long c, unsigned long long r) {
    return (c >> 1) | (r << 63);   // value at x+1
}
__device__ __forceinline__ unsigned long long shl2(unsigned long long c, unsigned long long l) {
    return (c << 2) | (l >> 62);
}
__device__ __forceinline__ unsigned long long shr2(unsigned long long c, unsigned long long r) {
    return (c >> 2) | (r << 62);
}

// ---- Kernel A: ballot-mask (16-row strip + 4 halo) + bitwise morphology ----
// Writes interleaved {tword, bword} as one 16B store per word.
__global__ __launch_bounds__(256) void maskbound_kernel(
    const float* __restrict__ tgt, ulonglong2* __restrict__ comb)
{
    __shared__ unsigned long long tmask[MROWS][WPR];

    const int img   = blockIdx.x / SPI;
    const int strip = blockIdx.x % SPI;
    const int r0    = strip * RSTRIP;
    const float* tb = tgt + img * HW;

    const int wave = threadIdx.x >> 6;
    const int lane = threadIdx.x & 63;

    // Phase 1: 160 mask words; wave owns words [wave*40, wave*40+40), 4-way MLP
    unsigned long long* tmflat = &tmask[0][0];
    #pragma unroll
    for (int g = 0; g < WPW / 4; g++) {      // 10 groups of 4 independent loads
        int wi0 = wave * WPW + g * 4;
        float v0 = 0.f, v1 = 0.f, v2 = 0.f, v3 = 0.f;
        int gr0 = r0 - 2 + ((wi0 + 0) >> 3);
        int gr1 = r0 - 2 + ((wi0 + 1) >> 3);
        int gr2 = r0 - 2 + ((wi0 + 2) >> 3);
        int gr3 = r0 - 2 + ((wi0 + 3) >> 3);
        if ((unsigned)gr0 < (unsigned)Hdim) v0 = tb[gr0 * Wdim + ((wi0 + 0) & 7) * 64 + lane];
        if ((unsigned)gr1 < (unsigned)Hdim) v1 = tb[gr1 * Wdim + ((wi0 + 1) & 7) * 64 + lane];
        if ((unsigned)gr2 < (unsigned)Hdim) v2 = tb[gr2 * Wdim + ((wi0 + 2) & 7) * 64 + lane];
        if ((unsigned)gr3 < (unsigned)Hdim) v3 = tb[gr3 * Wdim + ((wi0 + 3) & 7) * 64 + lane];
        unsigned long long m0 = __ballot(v0 > 0.5f);
        unsigned long long m1 = __ballot(v1 > 0.5f);
        unsigned long long m2 = __ballot(v2 > 0.5f);
        unsigned long long m3 = __ballot(v3 > 0.5f);
        if (lane == 0) {
            tmflat[wi0 + 0] = m0;
            tmflat[wi0 + 1] = m1;
            tmflat[wi0 + 2] = m2;
            tmflat[wi0 + 3] = m3;
        }
    }
    __syncthreads();

    // Phase 2: boundary for the 16x8 strip words (threads 0..127)
    if (threadIdx.x < RSTRIP * WPR) {
        int row  = threadIdx.x >> 3;    // 0..15
        int word = threadIdx.x & 7;
        int mr = row + 2;

        #define CW(r)  tmask[r][word]
        #define LW(r)  (word > 0 ? tmask[r][word - 1] : 0ULL)
        #define RW(r)  (word < WPR - 1 ? tmask[r][word + 1] : 0ULL)
        unsigned long long c0 = CW(mr),   l0 = LW(mr),   rr0 = RW(mr);
        unsigned long long cm = CW(mr-1), lm = LW(mr-1), rm  = RW(mr-1);
        unsigned long long cp = CW(mr+1), lp = LW(mr+1), rp  = RW(mr+1);
        unsigned long long cm2 = CW(mr-2);
        unsigned long long cp2 = CW(mr+2);
        #undef CW
        #undef LW
        #undef RW

        unsigned long long er =
            c0 & shl1(c0,l0) & shr1(c0,rr0) & shl2(c0,l0) & shr2(c0,rr0)
               & cm & shl1(cm,lm) & shr1(cm,rm)
               & cp & shl1(cp,lp) & shr1(cp,rp)
               & cm2 & cp2;
        unsigned long long di =
            c0 | shl1(c0,l0) | shr1(c0,rr0) | shl2(c0,l0) | shr2(c0,rr0)
               | cm | shl1(cm,lm) | shr1(cm,rm)
               | cp | shl1(cp,lp) | shr1(cp,rp)
               | cm2 | cp2;

        ulonglong2 pair;
        pair.x = c0;            // t-word
        pair.y = di & ~er;      // boundary word
        comb[img * WPI + (r0 + row) * WPR + word] = pair;   // 16B store
    }
}

// ---- Kernel B: pure streaming elementwise + per-block partials ----
__global__ __launch_bounds__(256, 4) void combined_loss_kernel(
    const float* __restrict__ inp, const ulonglong2* __restrict__ comb,
    float* __restrict__ partials)
{
    const int tid = blockIdx.x * 256 + threadIdx.x;
    float s_focal = 0.f, s_inter = 0.f, s_p = 0.f, s_bw = 0.f;
    int s_tc = 0;

    #pragma unroll
    for (int it = 0; it < CITERS; it++) {
        const int f4 = tid + it * CTHREADS;
        const float4 v = ((const float4*)inp)[f4];
        const int wi = f4 >> 4;              // mask word index
        const int sh = (f4 & 15) * 4;        // nibble shift
        const ulonglong2 cb = comb[wi];      // one 16B load: {tword, bword}
        unsigned int tb4 = (unsigned int)((cb.x >> sh) & 0xFULL);
        unsigned int bb4 = (unsigned int)((cb.y >> sh) & 0xFULL);
        s_tc += __popc(tb4);
        const float xs[4] = {v.x, v.y, v.z, v.w};
        #pragma unroll
        for (int k = 0; k < 4; k++) {
            float xi = xs[k];
            bool tpos = (tb4 >> k) & 1;
            float e  = __expf(-fabsf(xi));                  // exp(-|x|)
            float bce = fmaxf(xi, 0.f) - (tpos ? xi : 0.f) + __logf(1.f + e);
            float rden = __builtin_amdgcn_rcpf(1.f + e);
            float p = (xi >= 0.f ? 1.f : e) * rden;         // sigmoid
            float pt = tpos ? p : 1.f - p;                  // == exp(-bce)
            float om = 1.f - pt;
            s_focal += 0.25f * om * om * bce;
            s_p     += p;
            s_inter += tpos ? p : 0.f;
            float wgt = ((bb4 >> k) & 1) ? 6.0f : 1.0f;     // 1 + THETA*boundary
            s_bw += bce * wgt;
        }
    }
    float s_t = (float)s_tc;

    // Reduce: wave shuffle -> LDS -> per-block partial store (NO atomics)
    __shared__ float smem[4][5];
    const int wave = threadIdx.x >> 6;
    const int lane = threadIdx.x & 63;
    #pragma unroll
    for (int off = 32; off > 0; off >>= 1) {
        s_focal += __shfl_down(s_focal, off);
        s_inter += __shfl_down(s_inter, off);
        s_p     += __shfl_down(s_p,     off);
        s_t     += __shfl_down(s_t,     off);
        s_bw    += __shfl_down(s_bw,    off);
    }
    if (lane == 0) {
        smem[wave][0] = s_focal; smem[wave][1] = s_inter; smem[wave][2] = s_p;
        smem[wave][3] = s_t;     smem[wave][4] = s_bw;
    }
    __syncthreads();
    if (threadIdx.x < 5) {
        float a = smem[0][threadIdx.x] + smem[1][threadIdx.x]
                + smem[2][threadIdx.x] + smem[3][threadIdx.x];
        partials[blockIdx.x * 8 + threadIdx.x] = a;
    }
}

// ---- Kernel C: reduce NBLK_C partial slots, compute final scalar ----
__global__ __launch_bounds__(256) void finalize_kernel(
    const float* __restrict__ partials, float* __restrict__ out)
{
    __shared__ float smem[4][5];
    float a0 = 0.f, a1 = 0.f, a2 = 0.f, a3 = 0.f, a4 = 0.f;
    for (int b = threadIdx.x; b < NBLK_C; b += 256) {
        const float* s = partials + b * 8;
        a0 += s[0]; a1 += s[1]; a2 += s[2]; a3 += s[3]; a4 += s[4];
    }
    #pragma unroll
    for (int off = 32; off > 0; off >>= 1) {
        a0 += __shfl_down(a0, off);
        a1 += __shfl_down(a1, off);
        a2 += __shfl_down(a2, off);
        a3 += __shfl_down(a3, off);
        a4 += __shfl_down(a4, off);
    }
    int wave = threadIdx.x >> 6;
    int lane = threadIdx.x & 63;
    if (lane == 0) {
        smem[wave][0] = a0; smem[wave][1] = a1; smem[wave][2] = a2;
        smem[wave][3] = a3; smem[wave][4] = a4;
    }
    __syncthreads();
    if (threadIdx.x == 0) {
        double b0 = 0, b1 = 0, b2 = 0, b3 = 0, b4 = 0;
        #pragma unroll
        for (int w = 0; w < 4; w++) {
            b0 += smem[w][0]; b1 += smem[w][1]; b2 += smem[w][2];
            b3 += smem[w][3]; b4 += smem[w][4];
        }
        double invN = 1.0 / (double)(NIMG * HW);
        double focal_loss = b0 * invN;
        double dice = (2.0 * b1 + 1e-6) / (b2 + b3 + 1e-6);
        double boundary_loss = b4 * invN;
        out[0] = (float)(0.3 * focal_loss + 0.4 * (1.0 - dice) + 0.3 * boundary_loss);
    }
}

extern "C" void kernel_launch(void* const* d_in, const int* in_sizes, int n_in,
                              void* d_out, int out_size, void* d_ws, size_t ws_size,
                              hipStream_t stream) {
    const float* inp = (const float*)d_in[0];
    const float* tgt = (const float*)d_in[1];
    float* out = (float*)d_out;
    char* ws = (char*)d_ws;
    float* partials = (float*)ws;
    ulonglong2* comb = (ulonglong2*)(ws + (4u << 20));

    maskbound_kernel<<<NBLK_M, 256, 0, stream>>>(tgt, comb);
    combined_loss_kernel<<<NBLK_C, 256, 0, stream>>>(inp, comb, partials);
    finalize_kernel<<<1, 256, 0, stream>>>(partials, out);
}